// Round 8
// baseline (586.943 us; speedup 1.0000x reference)
//
#include <hip/hip_runtime.h>
#include <hip/hip_cooperative_groups.h>

namespace cg = cooperative_groups;

// ---------- types ----------
typedef __attribute__((ext_vector_type(8))) __bf16 bf16x8;
typedef __attribute__((ext_vector_type(2))) __bf16 bf16x2;
typedef __attribute__((ext_vector_type(4))) float  f32x4;

#define SCALE_Q 0.1803368801111204f   // 0.125 * log2(e): QK^T in log2 units

__device__ __forceinline__ unsigned short f2bf(float f) {
    return __builtin_bit_cast(unsigned short, (__bf16)f);
}
__device__ __forceinline__ unsigned int pack2(float a, float b) {
    bf16x2 t; t[0] = (__bf16)a; t[1] = (__bf16)b;
    return __builtin_bit_cast(unsigned int, t);
}

// [rows][512 bf16] LDS tile, 8-elem-chunk XOR-swizzled
__device__ __forceinline__ int idxW(int row, int ch) {
    return row * 512 + (((ch & ~7) | ((ch ^ row) & 7)) << 3);
}
// [rows][64 bf16] LDS tile, chunk-swizzled
__device__ __forceinline__ int swz8(int row, int chunk) {
    return row * 64 + ((chunk ^ (row & 7)) << 3);
}
__device__ __forceinline__ bf16x8 fragld(const unsigned short* lds, int row, int kk, int lane) {
    return *(const bf16x8*)(lds + swz8(row, kk * 4 + (lane >> 4)));
}

// async 16B/lane global->LDS
__device__ __forceinline__ void gload16(const unsigned short* g, unsigned short* l) {
    __builtin_amdgcn_global_load_lds((const __attribute__((address_space(1))) void*)g,
                                     (__attribute__((address_space(3))) void*)l, 16, 0, 0);
}
__device__ __forceinline__ void stage16(const unsigned short* g, int ldg,
                                        unsigned short* lds, int lane, int wv) {
    const unsigned short* gp = g + (size_t)(wv * 16 + (lane >> 3)) * ldg + (lane & 7) * 8;
#pragma unroll
    for (int i = 0; i < 2; ++i)
        gload16(gp + (size_t)(i * 8) * ldg, lds + (wv * 16 + i * 8) * 64);
}

// ---------- DPP 16-lane butterfly reduce (VALU only; groups = DPP rows) ----------
template<int CTRL>
__device__ __forceinline__ float dppf(float x) {
    return __builtin_bit_cast(float,
        __builtin_amdgcn_mov_dpp(__builtin_bit_cast(int, x), CTRL, 0xF, 0xF, true));
}
__device__ __forceinline__ float red16max(float x) {
    x = fmaxf(x, dppf<0xB1>(x));    // quad_perm [1,0,3,2]
    x = fmaxf(x, dppf<0x4E>(x));    // quad_perm [2,3,0,1]
    x = fmaxf(x, dppf<0x141>(x));   // row_half_mirror
    x = fmaxf(x, dppf<0x140>(x));   // row_mirror
    return x;
}
__device__ __forceinline__ float red16sum(float x) {
    x += dppf<0xB1>(x);
    x += dppf<0x4E>(x);
    x += dppf<0x141>(x);
    x += dppf<0x140>(x);
    return x;
}

// ---------- shared phase bodies ----------
__device__ __forceinline__ void body_ckw(int t, int lane, int wv,
                                         const float* Wv, const float* Wk,
                                         const float* Wq, const float* Wm,
                                         unsigned short* Wp) {
    int gw = t * 4 + wv;
    int w = gw >> 9, rem = gw & 511;
    int nb = rem >> 4, kb = rem & 15;
    const float* src = (w == 0) ? Wv : (w == 1) ? Wk : (w == 2) ? Wq : Wm;
    const float* gp = src + (size_t)(nb * 16 + (lane & 15)) * 512 + kb * 32 + (lane >> 4) * 8;
    float4 v0 = *(const float4*)gp, v1 = *(const float4*)(gp + 4);
    uint4 o;
    o.x = pack2(v0.x, v0.y); o.y = pack2(v0.z, v0.w);
    o.z = pack2(v1.x, v1.y); o.w = pack2(v1.z, v1.w);
    *(uint4*)(Wp + ((size_t)w << 18) + ((size_t)((nb * 16 + kb) * 64 + lane)) * 8) = o;
}

__device__ __forceinline__ void body_proj(int pid, unsigned short* As, int tid, int lane, int wv,
                                          const float* kin, const float* vin, const float* qin,
                                          const unsigned short* Wp,
                                          const float* bk, const float* bv, const float* bq,
                                          unsigned short* kh, unsigned short* vhT,
                                          unsigned short* qh) {
    int srcSel = (pid < 128) ? 0 : (pid < 256) ? 1 : 2;

    if (srcSel < 2) {
        int panel = (srcSel == 0) ? pid : pid - 128;
        const float* src = ((srcSel == 0) ? kin : vin) + (size_t)panel * 64 * 512;
#pragma unroll
        for (int it = 0; it < 16; ++it) {
            int id = it * 256 + tid, row = id >> 6, ch = id & 63;
            const float* gp = src + (size_t)row * 512 + ch * 8;
            float4 a0 = *(const float4*)gp, a1 = *(const float4*)(gp + 4);
            uint4 w;
            w.x = pack2(a0.x, a0.y); w.y = pack2(a0.z, a0.w);
            w.z = pack2(a1.x, a1.y); w.w = pack2(a1.z, a1.w);
            *(uint4*)(&As[idxW(row, ch)]) = w;
        }
    } else {
        int qi = pid - 256, b = qi >> 4, pp = qi & 15;
        const float* src = qin + (size_t)b * 512 * 1024 + pp * 64;
#pragma unroll
        for (int cc = 0; cc < 8; ++cc) {
            int c0 = cc * 64 + (tid >> 4) * 4;
            int pl = (tid & 15) * 4;
            float rr[4][4];
#pragma unroll
            for (int i = 0; i < 4; ++i) {
                float4 t4 = *(const float4*)(src + (size_t)(c0 + i) * 1024 + pl);
                rr[i][0] = t4.x; rr[i][1] = t4.y; rr[i][2] = t4.z; rr[i][3] = t4.w;
            }
#pragma unroll
            for (int j = 0; j < 4; ++j) {
                int row = pl + j, chunk = c0 >> 3, off = c0 & 7;
                uint2 w2;
                w2.x = pack2(rr[0][j], rr[1][j]);
                w2.y = pack2(rr[2][j], rr[3][j]);
                *(uint2*)(&As[row * 512 + (((chunk & ~7) | ((chunk ^ row) & 7)) << 3) + off]) = w2;
            }
        }
    }
    __syncthreads();

    int wsel = (srcSel == 0) ? 1 : (srcSel == 1) ? 0 : 2;   // pack order [Wv,Wk,Wq,Wm]
    const unsigned short* Wb = Wp + ((size_t)wsel << 18);
    f32x4 acc[4][8] = {};
#pragma unroll 2
    for (int kb = 0; kb < 16; ++kb) {
        bf16x8 af[4], bf8[8];
#pragma unroll
        for (int j = 0; j < 8; ++j)
            bf8[j] = *(const bf16x8*)(Wb + ((size_t)(((wv * 8 + j) * 16 + kb) * 64 + lane)) * 8);
#pragma unroll
        for (int i = 0; i < 4; ++i)
            af[i] = *(const bf16x8*)(&As[idxW(i * 16 + (lane & 15), kb * 4 + (lane >> 4))]);
#pragma unroll
        for (int j = 0; j < 8; ++j)
#pragma unroll
            for (int i = 0; i < 4; ++i)
                acc[i][j] = __builtin_amdgcn_mfma_f32_16x16x32_bf16(af[i], bf8[j], acc[i][j], 0, 0, 0);
    }

    if (srcSel == 1) {
        int panel = pid - 128, b = panel >> 4;
        int win = (panel & 15) * 64;
#pragma unroll
        for (int j = 0; j < 8; ++j) {
            int o = wv * 128 + j * 16 + (lane & 15);
            float bb = bv[o];
            int n = o >> 6, d = o & 63;
            size_t bnbase = ((size_t)(b * 8 + n)) * 65536 + (size_t)d * 1024 + win;
#pragma unroll
            for (int i = 0; i < 4; ++i) {
                int l0 = i * 16 + ((lane >> 4) << 2);
                uint2 w2;
                w2.x = pack2(acc[i][j][0] + bb, acc[i][j][1] + bb);
                w2.y = pack2(acc[i][j][2] + bb, acc[i][j][3] + bb);
                int off = (((l0 >> 3) ^ (d & 7)) << 3) + (l0 & 7);
                *(uint2*)(&vhT[bnbase + off]) = w2;
            }
        }
    } else {
        const float* bias = (srcSel == 0) ? bk : bq;
        float scl = (srcSel == 0) ? 1.f : SCALE_Q;
        __syncthreads();
#pragma unroll
        for (int j = 0; j < 8; ++j) {
            int o = wv * 128 + j * 16 + (lane & 15);
            float bb = bias[o];
            int Cd = o >> 3, ob = o & 7;
#pragma unroll
            for (int i = 0; i < 4; ++i)
#pragma unroll
                for (int reg = 0; reg < 4; ++reg) {
                    int l = i * 16 + ((lane >> 4) << 2) + reg;
                    int Cs = (Cd & ~7) | ((Cd ^ l) & 7);
                    As[l * 512 + Cs * 8 + ob] = f2bf((acc[i][j][reg] + bb) * scl);
                }
        }
        __syncthreads();
        unsigned short* dst;
        int b, rbase;
        if (srcSel == 0) { b = pid >> 4; rbase = (pid & 15) * 64; dst = kh; }
        else { int qi = pid - 256; b = qi >> 4; rbase = (qi & 15) * 64; dst = qh; }
#pragma unroll
        for (int e = 0; e < 16; ++e) {
            int n = e >> 1, l = (e & 1) * 32 + (tid >> 3), ch = tid & 7;
            uint4 w = *(const uint4*)(&As[l * 512 + (n * 8 + ch) * 8]);
            *(uint4*)(&dst[(((size_t)(b * 8 + n)) * 1024 + rbase + l) * 64 + ch * 8]) = w;
        }
    }
}

__device__ __forceinline__ void body_attn(int bn, int pt, unsigned short* Qs,
                                          unsigned short* Ks0, unsigned short* Ks1,
                                          unsigned short* Vs0, unsigned short* Vs1,
                                          int tid, int lane, int wv,
                                          unsigned short* qa,
                                          const unsigned short* kh, const unsigned short* vhT,
                                          const int* mask) {
    int b = bn >> 3;
    int p0 = pt * 64;
    const unsigned short* kbase = kh + ((size_t)bn) * 65536;
    const unsigned short* vbase = vhT + ((size_t)bn) * 65536;
    const int* mbase = mask + (size_t)b * 1024;

    stage16(qa + (((size_t)bn) * 1024 + p0) * 64, 64, Qs, lane, wv);
    stage16(kbase, 64, Ks0, lane, wv);
    stage16(vbase, 1024, Vs0, lane, wv);
    __syncthreads();
    bf16x8 aq0 = fragld(Qs, wv * 16 + (lane & 15), 0, lane);
    bf16x8 aq1 = fragld(Qs, wv * 16 + (lane & 15), 1, lane);
    unsigned short* Pw = &Qs[wv * 16 * 64];

    float mrow[4], lrow[4];
    f32x4 o4[4] = {};
#pragma unroll
    for (int r = 0; r < 4; ++r) { mrow[r] = -3e38f; lrow[r] = 0.f; }

#pragma unroll 2
    for (int t = 0; t < 16; ++t) {
        unsigned short* Kc = (t & 1) ? Ks1 : Ks0;
        unsigned short* Vc = (t & 1) ? Vs1 : Vs0;
        unsigned short* Kn = (t & 1) ? Ks0 : Ks1;
        unsigned short* Vn = (t & 1) ? Vs0 : Vs1;
        if (t < 15) {
            int l1 = (t + 1) * 64;
            stage16(kbase + (size_t)l1 * 64, 64, Kn, lane, wv);
            stage16(vbase + l1, 1024, Vn, lane, wv);
        }
        int l0 = t * 64;
        int mc[4];
#pragma unroll
        for (int j = 0; j < 4; ++j) mc[j] = mbase[l0 + j * 16 + (lane & 15)];

        f32x4 s[4] = {};
#pragma unroll
        for (int j = 0; j < 4; ++j) {
            bf16x8 bk0 = fragld(Kc, j * 16 + (lane & 15), 0, lane);
            bf16x8 bk1 = fragld(Kc, j * 16 + (lane & 15), 1, lane);
            s[j] = __builtin_amdgcn_mfma_f32_16x16x32_bf16(aq0, bk0, s[j], 0, 0, 0);
            s[j] = __builtin_amdgcn_mfma_f32_16x16x32_bf16(aq1, bk1, s[j], 0, 0, 0);
        }
#pragma unroll
        for (int j = 0; j < 4; ++j) {
            if (mc[j] != 0) {
#pragma unroll
                for (int reg = 0; reg < 4; ++reg) s[j][reg] = -1e9f;
            }
        }
        float pvv[4][4], corr[4];
#pragma unroll
        for (int reg = 0; reg < 4; ++reg) {
            float mx = red16max(fmaxf(fmaxf(s[0][reg], s[1][reg]), fmaxf(s[2][reg], s[3][reg])));
            float mnew = fmaxf(mrow[reg], mx);
            corr[reg] = exp2f(mrow[reg] - mnew);
            mrow[reg] = mnew;
            float sum = 0.f;
#pragma unroll
            for (int j = 0; j < 4; ++j) {
                float p = exp2f(s[j][reg] - mnew);
                pvv[j][reg] = p; sum += p;
            }
            lrow[reg] = lrow[reg] * corr[reg] + red16sum(sum);
        }
#pragma unroll
        for (int j = 0; j < 4; ++j) {
            int c = j * 16 + (lane & 15);
#pragma unroll
            for (int reg = 0; reg < 4; ++reg) {
                int pr = ((lane >> 4) << 2) + reg;
                Pw[pr * 64 + (((c >> 3) ^ (pr & 7)) << 3) + (c & 7)] = f2bf(pvv[j][reg]);
            }
        }
#pragma unroll
        for (int jd = 0; jd < 4; ++jd)
#pragma unroll
            for (int reg = 0; reg < 4; ++reg) o4[jd][reg] *= corr[reg];
#pragma unroll
        for (int kk = 0; kk < 2; ++kk) {
            bf16x8 ap = fragld(Pw, (lane & 15), kk, lane);
#pragma unroll
            for (int jd = 0; jd < 4; ++jd) {
                bf16x8 bvf = fragld(Vc, jd * 16 + (lane & 15), kk, lane);
                o4[jd] = __builtin_amdgcn_mfma_f32_16x16x32_bf16(ap, bvf, o4[jd], 0, 0, 0);
            }
        }
        __syncthreads();
    }
    float inv[4];
#pragma unroll
    for (int reg = 0; reg < 4; ++reg) inv[reg] = 1.f / lrow[reg];
    unsigned short* Ow = Pw;
#pragma unroll
    for (int jd = 0; jd < 4; ++jd) {
        int d = jd * 16 + (lane & 15);
        int ch = d >> 3, doff = d & 7;
#pragma unroll
        for (int reg = 0; reg < 4; ++reg) {
            int pr = ((lane >> 4) << 2) + reg;
            Ow[pr * 64 + ((ch ^ (pr & 7)) << 3) + doff] = f2bf(o4[jd][reg] * inv[reg]);
        }
    }
    size_t base = ((size_t)bn * 16 + pt) * 4096;
#pragma unroll
    for (int h = 0; h < 2; ++h) {
        int p = lane & 15;
        int ch = h * 4 + (lane >> 4);
        uint4 w = *(const uint4*)(&Ow[p * 64 + ((ch ^ (p & 7)) << 3)]);
        *(uint4*)(qa + base + (size_t)(wv * 2 + h) * 512 + (size_t)lane * 8) = w;
    }
    __syncthreads();
}

__device__ __forceinline__ void body_final(int t3, int lane, int wv,
                                           const unsigned short* aP, const unsigned short* Wm8,
                                           const float* bm, float* out) {
    int b = t3 >> 5, m0 = ((t3 >> 3) & 3) * 128, n0 = (t3 & 7) * 128;
    int wr = wv >> 1, wc = wv & 1;
    int onb = m0 / 16 + wr * 4;
    int pnb = n0 / 16 + wc * 4;
    f32x4 acc[4][4] = {};
#pragma unroll 2
    for (int kb = 0; kb < 16; ++kb) {
        int nh = kb >> 1, h = kb & 1, bn = b * 8 + nh;
        bf16x8 af[4], bf8[4];
#pragma unroll
        for (int i = 0; i < 4; ++i)
            af[i] = *(const bf16x8*)(Wm8 + ((size_t)(((onb + i) * 16 + kb) * 64 + lane)) * 8);
#pragma unroll
        for (int j = 0; j < 4; ++j) {
            int pb = pnb + j;
            bf8[j] = *(const bf16x8*)(aP + ((size_t)bn * 16 + (pb >> 2)) * 4096 +
                                      (size_t)((pb & 3) * 2 + h) * 512 + (size_t)lane * 8);
        }
#pragma unroll
        for (int i = 0; i < 4; ++i)
#pragma unroll
            for (int j = 0; j < 4; ++j)
                acc[i][j] = __builtin_amdgcn_mfma_f32_16x16x32_bf16(af[i], bf8[j], acc[i][j], 0, 0, 0);
    }
#pragma unroll
    for (int i = 0; i < 4; ++i)
#pragma unroll
        for (int reg = 0; reg < 4; ++reg) {
            int o = m0 + wr * 64 + i * 16 + ((lane >> 4) << 2) + reg;
            float bb = bm[o];
#pragma unroll
            for (int j = 0; j < 4; ++j) {
                int p = n0 + wc * 64 + j * 16 + (lane & 15);
                out[((size_t)(b * 512 + o)) * 1024 + p] = fmaxf(acc[i][j][reg] + bb, 0.f);
            }
        }
}

// ================= cooperative mega kernel (grid-size agnostic) =================
__global__ __launch_bounds__(256, 2) void mega(
    const float* __restrict__ kin, const float* __restrict__ vin,
    const float* __restrict__ qin, const int* __restrict__ mask,
    const float* __restrict__ Wv, const float* __restrict__ bv,
    const float* __restrict__ Wk, const float* __restrict__ bk,
    const float* __restrict__ Wq, const float* __restrict__ bq,
    const float* __restrict__ Wm, const float* __restrict__ bm,
    float* __restrict__ out,
    unsigned short* __restrict__ kh, unsigned short* __restrict__ vhT,
    unsigned short* qh, unsigned short* __restrict__ Wp)
{
    __shared__ alignas(16) unsigned short smem[64 * 512];   // 64 KB
    cg::grid_group grid = cg::this_grid();
    int tid = threadIdx.x, lane = tid & 63, wv = tid >> 6;
    int bid = blockIdx.x, G = gridDim.x;

    for (int t = bid; t < 512; t += G)
        body_ckw(t, lane, wv, Wv, Wk, Wq, Wm, Wp);
    __threadfence();
    grid.sync();

    for (int pid = bid; pid < 384; pid += G) {
        __syncthreads();
        body_proj(pid, smem, tid, lane, wv, kin, vin, qin, Wp, bk, bv, bq, kh, vhT, qh);
    }
    __threadfence();
    grid.sync();

    for (int t = bid; t < 1024; t += G)
        body_attn(t & 63, t >> 6, smem, smem + 4096, smem + 8192, smem + 12288, smem + 16384,
                  tid, lane, wv, qh, kh, vhT, mask);
    __threadfence();
    grid.sync();

    for (int t = bid; t < 256; t += G)
        body_final(t, lane, wv, qh, Wp + 3 * 262144, bm, out);
}

// ================= fallback kernels (round-6 proven path) =================
__global__ __launch_bounds__(256) void ck_w(const float* __restrict__ Wv, const float* __restrict__ Wk,
                                            const float* __restrict__ Wq, const float* __restrict__ Wm,
                                            unsigned short* __restrict__ Wp) {
    body_ckw(blockIdx.x, threadIdx.x & 63, threadIdx.x >> 6, Wv, Wk, Wq, Wm, Wp);
}

__global__ __launch_bounds__(256, 2) void g_proj(const float* __restrict__ kin,
                                                 const float* __restrict__ vin,
                                                 const float* __restrict__ qin,
                                                 const unsigned short* __restrict__ Wp,
                                                 const float* __restrict__ bk,
                                                 const float* __restrict__ bv,
                                                 const float* __restrict__ bq,
                                                 unsigned short* __restrict__ kh,
                                                 unsigned short* __restrict__ vhT,
                                                 unsigned short* __restrict__ qh) {
    __shared__ alignas(16) unsigned short As[64 * 512];
    body_proj(blockIdx.x, As, threadIdx.x, threadIdx.x & 63, threadIdx.x >> 6,
              kin, vin, qin, Wp, bk, bv, bq, kh, vhT, qh);
}

__global__ __launch_bounds__(256) void k_attn(unsigned short* qa,
                                              const unsigned short* __restrict__ kh,
                                              const unsigned short* __restrict__ vhT,
                                              const int* __restrict__ mask) {
    __shared__ alignas(16) unsigned short Qs[64 * 64];
    __shared__ alignas(16) unsigned short Ks[2][64 * 64];
    __shared__ alignas(16) unsigned short Vs[2][64 * 64];
    body_attn(blockIdx.x, blockIdx.y, Qs, Ks[0], Ks[1], Vs[0], Vs[1],
              threadIdx.x, threadIdx.x & 63, threadIdx.x >> 6, qa, kh, vhT, mask);
}

__global__ __launch_bounds__(256, 2) void g_final(const unsigned short* __restrict__ aP,
                                                  const unsigned short* __restrict__ Wm8,
                                                  const float* __restrict__ bm,
                                                  float* __restrict__ out) {
    int bid = blockIdx.z * 32 + blockIdx.x * 8 + blockIdx.y;   // b*32 + mi*8 + ni
    body_final(bid, threadIdx.x & 63, threadIdx.x >> 6, aP, Wm8, bm, out);
}

extern "C" void kernel_launch(void* const* d_in, const int* in_sizes, int n_in,
                              void* d_out, int out_size, void* d_ws, size_t ws_size,
                              hipStream_t stream) {
    const float* v  = (const float*)d_in[0];
    const float* k  = (const float*)d_in[1];
    const float* q  = (const float*)d_in[2];
    const int*   mask = (const int*)d_in[3];   // JAX bool -> int32
    const float* Wv = (const float*)d_in[4];
    const float* bv = (const float*)d_in[5];
    const float* Wk = (const float*)d_in[6];
    const float* bk = (const float*)d_in[7];
    const float* Wq = (const float*)d_in[8];
    const float* bq = (const float*)d_in[9];
    const float* Wm = (const float*)d_in[10];
    const float* bm = (const float*)d_in[11];
    float* out = (float*)d_out;

    const size_t E = (size_t)8 * 8 * 1024 * 64;   // 4,194,304 shorts = 8 MB per region
    unsigned short* kh  = (unsigned short*)d_ws;  // pre-swizzled [bn][l][dsw]
    unsigned short* vhT = kh + E;                 // pre-swizzled [bn][d][lsw]
    unsigned short* qh  = vhT + E;                // pre-swizzled [bn][p][dsw]; attnP alias
    unsigned short* Wp  = qh + E;                 // 4 x 512KB frag-packed weights

    void* args[] = {
        (void*)&k, (void*)&v, (void*)&q, (void*)&mask,
        (void*)&Wv, (void*)&bv, (void*)&Wk, (void*)&bk,
        (void*)&Wq, (void*)&bq, (void*)&Wm, (void*)&bm,
        (void*)&out, (void*)&kh, (void*)&vhT, (void*)&qh, (void*)&Wp
    };
    hipError_t e = hipLaunchCooperativeKernel((void*)mega, dim3(512), dim3(256), args, 0, stream);
    if (e != hipSuccess)
        e = hipLaunchCooperativeKernel((void*)mega, dim3(256), dim3(256), args, 0, stream);
    if (e != hipSuccess) {
        (void)hipGetLastError();   // clear sticky error from failed coop attempts
        dim3 blk(256);
        ck_w  <<<512, blk, 0, stream>>>(Wv, Wk, Wq, Wm, Wp);
        g_proj<<<384, blk, 0, stream>>>(k, v, q, Wp, bk, bv, bq, kh, vhT, qh);
        k_attn<<<dim3(64, 16), blk, 0, stream>>>(qh, kh, vhT, mask);
        g_final<<<dim3(4, 8, 8), blk, 0, stream>>>(qh, Wp + 3 * 262144, bm, out);
    }
}